// Round 1
// baseline (221.753 us; speedup 1.0000x reference)
//
#include <hip/hip_runtime.h>

#define Bn 8
#define Cn 512
#define Hn 8
#define Dn 64
#define Nn 1024
#define SCALEQ 0.125f

typedef unsigned short u16;
typedef unsigned short u16x8 __attribute__((ext_vector_type(8)));
typedef unsigned short u16x4 __attribute__((ext_vector_type(4)));
typedef float f32x4 __attribute__((ext_vector_type(4)));
typedef __bf16 bf16x8 __attribute__((ext_vector_type(8)));

__device__ __forceinline__ u16 f2bf(float f){
  unsigned u = __float_as_uint(f);
  u += 0x7fffu + ((u >> 16) & 1u);   // RNE
  return (u16)(u >> 16);
}
__device__ __forceinline__ float bf2f(u16 h){
  return __uint_as_float(((unsigned)h) << 16);
}
__device__ __forceinline__ f32x4 mfma16(u16x8 a, u16x8 b, f32x4 c){
  return __builtin_amdgcn_mfma_f32_16x16x32_bf16(
      __builtin_bit_cast(bf16x8, a), __builtin_bit_cast(bf16x8, b), c, 0, 0, 0);
}

// ---------------- pre-pass: f32 -> bf16 weight convert ----------------
__global__ __launch_bounds__(256) void k_convert(const float* __restrict__ src,
                                                 u16* __restrict__ dst, int n4){
  int i = blockIdx.x * 256 + threadIdx.x;
  if (i >= n4) return;
  float4 f = reinterpret_cast<const float4*>(src)[i];
  u16x4 o;
  o[0] = f2bf(f.x); o[1] = f2bf(f.y); o[2] = f2bf(f.z); o[3] = f2bf(f.w);
  reinterpret_cast<u16x4*>(dst)[i] = o;
}

// ---------------- pre-pass: fmap [B][C][N] f32 -> fmapT [B][N][C] bf16 ----------------
__global__ __launch_bounds__(256) void k_transpose(const float* __restrict__ fmap,
                                                   u16* __restrict__ fmapT){
  __shared__ float tile[32][33];
  const int n0 = blockIdx.x * 32, c0 = blockIdx.y * 32, b = blockIdx.z;
  const int tx = threadIdx.x & 31, ty = threadIdx.x >> 5;   // 32 x 8
  const float* src = fmap + ((size_t)b * Cn + c0) * Nn + n0;
#pragma unroll
  for (int i = 0; i < 4; i++) tile[ty + 8*i][tx] = src[(size_t)(ty + 8*i) * Nn + tx];
  __syncthreads();
  u16* dst = fmapT + ((size_t)b * Nn + n0) * Cn + c0;
#pragma unroll
  for (int i = 0; i < 4; i++) dst[(size_t)(ty + 8*i) * Cn + tx] = f2bf(tile[tx][ty + 8*i]);
}

// ---------------- shared NT GEMM core: D[i][j] = sum_k A[i*lda+k] * B[j*ldb+k] ----------------
// per-wave 64x64 tile; A rows indexed by lane&15, k by 8*(lane>>4)+jj (16B contiguous loads)
__device__ __forceinline__ void gemm_nt_64x64(const u16* __restrict__ Ap, int lda,
                                              const u16* __restrict__ Bp, int ldb,
                                              int K, f32x4 acc[4][4]){
  const int lane = threadIdx.x & 63;
  const int r = lane & 15, g = lane >> 4;
  const u16* pa = Ap + (size_t)r * lda + 8 * g;
  const u16* pb = Bp + (size_t)r * ldb + 8 * g;
  for (int kc = 0; kc < K; kc += 32){
    u16x8 af[4], bf[4];
#pragma unroll
    for (int t = 0; t < 4; t++) af[t] = *reinterpret_cast<const u16x8*>(pa + (size_t)t*16*lda + kc);
#pragma unroll
    for (int t = 0; t < 4; t++) bf[t] = *reinterpret_cast<const u16x8*>(pb + (size_t)t*16*ldb + kc);
#pragma unroll
    for (int i = 0; i < 4; i++)
#pragma unroll
      for (int j = 0; j < 4; j++)
        acc[i][j] = mfma16(af[i], bf[j], acc[i][j]);
  }
}

// ---------------- GEMM1: qkvL = Wqkvl @ fmap  (per batch) ----------------
// Q/K/L written token-major [b][n][512] bf16 (Q pre-scaled); V written [b][h][d][n] bf16.
__global__ __launch_bounds__(256) void k_gemm1(const u16* __restrict__ fmapT, // [B][N][C]
                                               const u16* __restrict__ W1,    // [2048][C]
                                               u16* __restrict__ Qb, u16* __restrict__ Kb,
                                               u16* __restrict__ Vt, u16* __restrict__ Lb){
  const int ob = blockIdx.x;           // 16 o-blocks of 128
  const int nb = blockIdx.y;           // 8 n-blocks of 128
  const int b  = blockIdx.z;
  const int w = threadIdx.x >> 6, wi = w >> 1, wj = w & 1;
  const int lane = threadIdx.x & 63, r = lane & 15, g = lane >> 4;
  const int seg = ob >> 2;             // 0=Q 1=K 2=V 3=L (128*4 = 512-aligned segments)

  f32x4 acc[4][4];
  const f32x4 z = {0.f, 0.f, 0.f, 0.f};
#pragma unroll
  for (int i = 0; i < 4; i++)
#pragma unroll
    for (int j = 0; j < 4; j++) acc[i][j] = z;

  const u16* fbase = fmapT + (size_t)b * Nn * Cn;

  if (seg != 2){
    // orientation A: i = token n, j = out-channel o  -> coalesced [n][c] writes
    const u16* Ap = fbase + (size_t)(nb*128 + wi*64) * Cn;
    const u16* Bp = W1 + (size_t)(ob*128 + wj*64) * Cn;
    gemm_nt_64x64(Ap, Cn, Bp, Cn, Cn, acc);
    u16* dst = (seg == 0) ? Qb : (seg == 1 ? Kb : Lb);
    const float sc = (seg == 0) ? SCALEQ : 1.0f;
#pragma unroll
    for (int it = 0; it < 4; it++)
#pragma unroll
      for (int jt = 0; jt < 4; jt++)
#pragma unroll
        for (int rr = 0; rr < 4; rr++){
          int n = nb*128 + wi*64 + it*16 + 4*g + rr;
          int o = ob*128 + wj*64 + jt*16 + r;
          dst[((size_t)b * Nn + n) * Cn + (o & 511)] = f2bf(acc[it][jt][rr] * sc);
        }
  } else {
    // orientation B: i = out-channel o, j = token n -> coalesced Vt [d][n] writes
    const u16* Ap = W1 + (size_t)(ob*128 + wi*64) * Cn;
    const u16* Bp = fbase + (size_t)(nb*128 + wj*64) * Cn;
    gemm_nt_64x64(Ap, Cn, Bp, Cn, Cn, acc);
#pragma unroll
    for (int it = 0; it < 4; it++)
#pragma unroll
      for (int jt = 0; jt < 4; jt++)
#pragma unroll
        for (int rr = 0; rr < 4; rr++){
          int o = ob*128 + wi*64 + it*16 + 4*g + rr;
          int oo = o - 1024;
          int h = oo >> 6, d = oo & 63;
          int n = nb*128 + wj*64 + jt*16 + r;
          Vt[(((size_t)b * Hn + h) * Dn + d) * Nn + n] = f2bf(acc[it][jt][rr]);
        }
  }
}

// ---------------- attention: flash-style, 1 wave = 16 q-rows, 32-key chunks ----------------
__global__ __launch_bounds__(256) void k_attn(const u16* __restrict__ Qb,  // [B][N][C] (q pre-scaled)
                                              const u16* __restrict__ Kb,  // [B][N][C]
                                              const u16* __restrict__ Vt,  // [B][H][D][N]
                                              const u16* __restrict__ Lb,  // [B][N][C]
                                              u16* __restrict__ tok){      // [B][N][C]
  __shared__ u16 P[4][16][40];   // per-wave P tile, stride 40 (16B-aligned rows, bank-spread)
  const int qblk = blockIdx.x;   // 16 blocks of 64 q-rows
  const int h = blockIdx.y, b = blockIdx.z;
  const int w = threadIdx.x >> 6, lane = threadIdx.x & 63;
  const int r = lane & 15, g = lane >> 4;
  const int q0 = qblk * 64 + w * 16;

  const u16* qrow = Qb + ((size_t)b * Nn + q0 + r) * Cn + h * Dn + 8 * g;
  u16x8 qf0 = *reinterpret_cast<const u16x8*>(qrow);
  u16x8 qf1 = *reinterpret_cast<const u16x8*>(qrow + 32);

  const u16* kbase = Kb + (size_t)b * Nn * Cn + h * Dn;
  const u16* vbase = Vt + ((size_t)b * Hn + h) * Dn * Nn;

  f32x4 accO[4];
  const f32x4 z = {0.f, 0.f, 0.f, 0.f};
#pragma unroll
  for (int dt = 0; dt < 4; dt++) accO[dt] = z;
  float m[4], lsum[4];
#pragma unroll
  for (int rr = 0; rr < 4; rr++){ m[rr] = -1e30f; lsum[rr] = 0.f; }

  for (int kt = 0; kt < Nn; kt += 32){
    u16x8 kf00 = *reinterpret_cast<const u16x8*>(kbase + (size_t)(kt + r) * Cn + 8*g);
    u16x8 kf01 = *reinterpret_cast<const u16x8*>(kbase + (size_t)(kt + r) * Cn + 32 + 8*g);
    u16x8 kf10 = *reinterpret_cast<const u16x8*>(kbase + (size_t)(kt + 16 + r) * Cn + 8*g);
    u16x8 kf11 = *reinterpret_cast<const u16x8*>(kbase + (size_t)(kt + 16 + r) * Cn + 32 + 8*g);
    f32x4 d0 = z, d1 = z;
    d0 = mfma16(qf0, kf00, d0); d0 = mfma16(qf1, kf01, d0);
    d1 = mfma16(qf0, kf10, d1); d1 = mfma16(qf1, kf11, d1);

    // online softmax (rows i = 4g+rr; cols kt+r and kt+16+r)
    float alpha[4];
#pragma unroll
    for (int rr = 0; rr < 4; rr++){
      float tm = fmaxf(d0[rr], d1[rr]);
      tm = fmaxf(tm, __shfl_xor(tm, 1));
      tm = fmaxf(tm, __shfl_xor(tm, 2));
      tm = fmaxf(tm, __shfl_xor(tm, 4));
      tm = fmaxf(tm, __shfl_xor(tm, 8));
      float mn = fmaxf(m[rr], tm);
      alpha[rr] = __expf(m[rr] - mn);
      m[rr] = mn;
    }
    asm volatile("" ::: "memory");   // keep prior-iter LDS reads ordered before these writes
#pragma unroll
    for (int rr = 0; rr < 4; rr++){
      float e0 = __expf(d0[rr] - m[rr]);
      float e1 = __expf(d1[rr] - m[rr]);
      P[w][4*g + rr][r]      = f2bf(e0);
      P[w][4*g + rr][r + 16] = f2bf(e1);
      float s = e0 + e1;
      s += __shfl_xor(s, 1); s += __shfl_xor(s, 2);
      s += __shfl_xor(s, 4); s += __shfl_xor(s, 8);
      lsum[rr] = lsum[rr] * alpha[rr] + s;
#pragma unroll
      for (int dt = 0; dt < 4; dt++) accO[dt][rr] *= alpha[rr];
    }
    asm volatile("s_waitcnt lgkmcnt(0)" ::: "memory");  // wave-internal P exchange

    u16x8 pf = *reinterpret_cast<const u16x8*>(&P[w][r][8*g]);  // A-frag: row r, keys 8g..8g+7
#pragma unroll
    for (int dt = 0; dt < 4; dt++){
      u16x8 vf = *reinterpret_cast<const u16x8*>(vbase + (size_t)(dt*16 + r) * Nn + kt + 8*g);
      accO[dt] = mfma16(pf, vf, accO[dt]);
    }
  }

  // epilogue: out = accO/lsum + L, token-major bf16
  float linv[4];
#pragma unroll
  for (int rr = 0; rr < 4; rr++) linv[rr] = 1.0f / lsum[rr];
  const u16* lrow = Lb + (size_t)b * Nn * Cn + h * Dn;
  u16* trow = tok + (size_t)b * Nn * Cn + h * Dn;
#pragma unroll
  for (int dt = 0; dt < 4; dt++)
#pragma unroll
    for (int rr = 0; rr < 4; rr++){
      int n = q0 + 4*g + rr;
      int d = dt*16 + r;
      float v = accO[dt][rr] * linv[rr] + bf2f(lrow[(size_t)n * Cn + d]);
      trow[(size_t)n * Cn + d] = f2bf(v);
    }
}

// ---------------- GEMM2: out = Wout @ tok + bout  -> f32 [B][C][N] ----------------
__global__ __launch_bounds__(256) void k_gemm2(const u16* __restrict__ tok, // [B][N][C]
                                               const u16* __restrict__ Wo,  // [C][C]
                                               const float* __restrict__ bout,
                                               float* __restrict__ out){
  const int ob = blockIdx.x;   // 4 o-blocks of 128
  const int nb = blockIdx.y;   // 8 n-blocks of 128
  const int b  = blockIdx.z;
  const int w = threadIdx.x >> 6, wi = w >> 1, wj = w & 1;
  const int lane = threadIdx.x & 63, r = lane & 15, g = lane >> 4;

  f32x4 acc[4][4];
  const f32x4 z = {0.f, 0.f, 0.f, 0.f};
#pragma unroll
  for (int i = 0; i < 4; i++)
#pragma unroll
    for (int j = 0; j < 4; j++) acc[i][j] = z;

  const u16* Ap = Wo + (size_t)(ob*128 + wi*64) * Cn;
  const u16* Bp = tok + (size_t)b * Nn * Cn + (size_t)(nb*128 + wj*64) * Cn;
  gemm_nt_64x64(Ap, Cn, Bp, Cn, Cn, acc);

#pragma unroll
  for (int it = 0; it < 4; it++)
#pragma unroll
    for (int jt = 0; jt < 4; jt++)
#pragma unroll
      for (int rr = 0; rr < 4; rr++){
        int o = ob*128 + wi*64 + it*16 + 4*g + rr;
        int n = nb*128 + wj*64 + jt*16 + r;
        out[((size_t)b * Cn + o) * Nn + n] = acc[it][jt][rr] + bout[o];
      }
}

extern "C" void kernel_launch(void* const* d_in, const int* in_sizes, int n_in,
                              void* d_out, int out_size, void* d_ws, size_t ws_size,
                              hipStream_t stream){
  const float* fmap  = (const float*)d_in[0];
  const float* Wqkvl = (const float*)d_in[1];
  const float* Wout  = (const float*)d_in[2];
  const float* bout  = (const float*)d_in[3];
  float* out = (float*)d_out;

  char* ws = (char*)d_ws;
  size_t off = 0;
  auto alloc = [&](size_t bytes) -> void* {
    void* p = ws + off;
    off += (bytes + 255) & ~(size_t)255;
    return p;
  };
  u16* W1bf  = (u16*)alloc((size_t)4*Cn*Cn*2);          // 2 MB
  u16* Wobf  = (u16*)alloc((size_t)Cn*Cn*2);            // 0.5 MB
  u16* fmapT = (u16*)alloc((size_t)Bn*Nn*Cn*2);         // 8.4 MB
  u16* Qb    = (u16*)alloc((size_t)Bn*Nn*Cn*2);
  u16* Kb    = (u16*)alloc((size_t)Bn*Nn*Cn*2);
  u16* Lb    = (u16*)alloc((size_t)Bn*Nn*Cn*2);
  u16* Vt    = (u16*)alloc((size_t)Bn*Hn*Dn*Nn*2);
  u16* tok   = fmapT;   // fmapT is dead after gemm1; reuse for attention output

  hipLaunchKernelGGL(k_convert, dim3((4*Cn*Cn/4 + 255)/256), dim3(256), 0, stream,
                     Wqkvl, W1bf, 4*Cn*Cn/4);
  hipLaunchKernelGGL(k_convert, dim3((Cn*Cn/4 + 255)/256), dim3(256), 0, stream,
                     Wout, Wobf, Cn*Cn/4);
  hipLaunchKernelGGL(k_transpose, dim3(Nn/32, Cn/32, Bn), dim3(256), 0, stream, fmap, fmapT);
  hipLaunchKernelGGL(k_gemm1, dim3(16, 8, Bn), dim3(256), 0, stream, fmapT, W1bf, Qb, Kb, Vt, Lb);
  hipLaunchKernelGGL(k_attn, dim3(16, Hn, Bn), dim3(256), 0, stream, Qb, Kb, Vt, Lb, tok);
  hipLaunchKernelGGL(k_gemm2, dim3(4, 8, Bn), dim3(256), 0, stream, tok, Wobf, bout, out);
}

// Round 2
// 220.366 us; speedup vs baseline: 1.0063x; 1.0063x over previous
//
#include <hip/hip_runtime.h>

#define Bn 8
#define Cn 512
#define Hn 8
#define Dn 64
#define Nn 1024
#define SCALEQ 0.125f

typedef unsigned short u16;
typedef unsigned short u16x8 __attribute__((ext_vector_type(8)));
typedef unsigned short u16x4 __attribute__((ext_vector_type(4)));
typedef float f32x4 __attribute__((ext_vector_type(4)));
typedef __bf16 bf16x8 __attribute__((ext_vector_type(8)));

__device__ __forceinline__ u16 f2bf(float f){
  unsigned u = __float_as_uint(f);
  u += 0x7fffu + ((u >> 16) & 1u);   // RNE
  return (u16)(u >> 16);
}
__device__ __forceinline__ float bf2f(u16 h){
  return __uint_as_float(((unsigned)h) << 16);
}
__device__ __forceinline__ f32x4 mfma16(u16x8 a, u16x8 b, f32x4 c){
  return __builtin_amdgcn_mfma_f32_16x16x32_bf16(
      __builtin_bit_cast(bf16x8, a), __builtin_bit_cast(bf16x8, b), c, 0, 0, 0);
}

// ---------------- pre-pass: f32 -> bf16 weight convert ----------------
__global__ __launch_bounds__(256) void k_convert(const float* __restrict__ src,
                                                 u16* __restrict__ dst, int n4){
  int i = blockIdx.x * 256 + threadIdx.x;
  if (i >= n4) return;
  float4 f = reinterpret_cast<const float4*>(src)[i];
  u16x4 o;
  o[0] = f2bf(f.x); o[1] = f2bf(f.y); o[2] = f2bf(f.z); o[3] = f2bf(f.w);
  reinterpret_cast<u16x4*>(dst)[i] = o;
}

// ---------------- pre-pass: fmap [B][C][N] f32 -> fmapT [B][N][C] bf16 ----------------
__global__ __launch_bounds__(256) void k_transpose(const float* __restrict__ fmap,
                                                   u16* __restrict__ fmapT){
  __shared__ float tile[32][33];
  const int n0 = blockIdx.x * 32, c0 = blockIdx.y * 32, b = blockIdx.z;
  const int tx = threadIdx.x & 31, ty = threadIdx.x >> 5;   // 32 x 8
  const float* src = fmap + ((size_t)b * Cn + c0) * Nn + n0;
#pragma unroll
  for (int i = 0; i < 4; i++) tile[ty + 8*i][tx] = src[(size_t)(ty + 8*i) * Nn + tx];
  __syncthreads();
  u16* dst = fmapT + ((size_t)b * Nn + n0) * Cn + c0;
#pragma unroll
  for (int i = 0; i < 4; i++) dst[(size_t)(ty + 8*i) * Cn + tx] = f2bf(tile[tx][ty + 8*i]);
}

// ---------------- shared NT GEMM core: D[i][j] = sum_k A[i*lda+k] * B[j*ldb+k] ----------------
__device__ __forceinline__ void gemm_nt_64x64(const u16* __restrict__ Ap, int lda,
                                              const u16* __restrict__ Bp, int ldb,
                                              int K, f32x4 acc[4][4]){
  const int lane = threadIdx.x & 63;
  const int r = lane & 15, g = lane >> 4;
  const u16* pa = Ap + (size_t)r * lda + 8 * g;
  const u16* pb = Bp + (size_t)r * ldb + 8 * g;
  for (int kc = 0; kc < K; kc += 32){
    u16x8 af[4], bf[4];
#pragma unroll
    for (int t = 0; t < 4; t++) af[t] = *reinterpret_cast<const u16x8*>(pa + (size_t)t*16*lda + kc);
#pragma unroll
    for (int t = 0; t < 4; t++) bf[t] = *reinterpret_cast<const u16x8*>(pb + (size_t)t*16*ldb + kc);
#pragma unroll
    for (int i = 0; i < 4; i++)
#pragma unroll
      for (int j = 0; j < 4; j++)
        acc[i][j] = mfma16(af[i], bf[j], acc[i][j]);
  }
}

// ---------------- GEMM1: qkvL = Wqkvl @ fmap  (per batch) ----------------
__global__ __launch_bounds__(256) void k_gemm1(const u16* __restrict__ fmapT, // [B][N][C]
                                               const u16* __restrict__ W1,    // [2048][C]
                                               u16* __restrict__ Qb, u16* __restrict__ Kb,
                                               u16* __restrict__ Vt, u16* __restrict__ Lb){
  const int ob = blockIdx.x;           // 16 o-blocks of 128
  const int nb = blockIdx.y;           // 8 n-blocks of 128
  const int b  = blockIdx.z;
  const int w = threadIdx.x >> 6, wi = w >> 1, wj = w & 1;
  const int lane = threadIdx.x & 63, r = lane & 15, g = lane >> 4;
  const int seg = ob >> 2;             // 0=Q 1=K 2=V 3=L

  f32x4 acc[4][4];
  const f32x4 z = {0.f, 0.f, 0.f, 0.f};
#pragma unroll
  for (int i = 0; i < 4; i++)
#pragma unroll
    for (int j = 0; j < 4; j++) acc[i][j] = z;

  const u16* fbase = fmapT + (size_t)b * Nn * Cn;

  if (seg != 2){
    const u16* Ap = fbase + (size_t)(nb*128 + wi*64) * Cn;
    const u16* Bp = W1 + (size_t)(ob*128 + wj*64) * Cn;
    gemm_nt_64x64(Ap, Cn, Bp, Cn, Cn, acc);
    u16* dst = (seg == 0) ? Qb : (seg == 1 ? Kb : Lb);
    const float sc = (seg == 0) ? SCALEQ : 1.0f;
#pragma unroll
    for (int it = 0; it < 4; it++)
#pragma unroll
      for (int jt = 0; jt < 4; jt++)
#pragma unroll
        for (int rr = 0; rr < 4; rr++){
          int n = nb*128 + wi*64 + it*16 + 4*g + rr;
          int o = ob*128 + wj*64 + jt*16 + r;
          dst[((size_t)b * Nn + n) * Cn + (o & 511)] = f2bf(acc[it][jt][rr] * sc);
        }
  } else {
    const u16* Ap = W1 + (size_t)(ob*128 + wi*64) * Cn;
    const u16* Bp = fbase + (size_t)(nb*128 + wj*64) * Cn;
    gemm_nt_64x64(Ap, Cn, Bp, Cn, Cn, acc);
#pragma unroll
    for (int it = 0; it < 4; it++)
#pragma unroll
      for (int jt = 0; jt < 4; jt++)
#pragma unroll
        for (int rr = 0; rr < 4; rr++){
          int o = ob*128 + wi*64 + it*16 + 4*g + rr;
          int oo = o - 1024;
          int h = oo >> 6, d = oo & 63;
          int n = nb*128 + wj*64 + jt*16 + r;
          Vt[(((size_t)b * Hn + h) * Dn + d) * Nn + n] = f2bf(acc[it][jt][rr]);
        }
  }
}

// ---------------- attention: swapped-operand flash, 1 wave = 16 q-rows, 64-key chunks ---------
// S^T = mfma(K, Q): lane holds S[keys 16t+4g+rr][query r] -> per-lane softmax row slices.
// P exchanged via padded LDS tile; O^T = mfma(V, P): acc per-lane query matches softmax layout.
__global__ __launch_bounds__(256) void k_attn(const u16* __restrict__ Qb,  // [B][N][C] (pre-scaled)
                                              const u16* __restrict__ Kb,  // [B][N][C]
                                              const u16* __restrict__ Vt,  // [B][H][D][N]
                                              const u16* __restrict__ Lb,  // [B][N][C]
                                              u16* __restrict__ tok){      // [B][N][C]
  __shared__ u16 P[4][16][72];   // per-wave [query][key 0..63], stride 72 u16 = 144B (16B-aligned)
  // XCD-bijective swizzle: 1024 blocks, the 16 q-blocks of one (b,h) share one XCD's L2
  const int bid = blockIdx.x;
  const int w0 = (bid & 7) * 128 + (bid >> 3);
  const int qblk = w0 & 15, h = (w0 >> 4) & 7, b = w0 >> 7;
  const int w = threadIdx.x >> 6, lane = threadIdx.x & 63;
  const int r = lane & 15, g = lane >> 4;
  const int q0 = qblk * 64 + w * 16;

  const u16* qrow = Qb + ((size_t)b * Nn + q0 + r) * Cn + h * Dn + 8 * g;
  u16x8 qf0 = *reinterpret_cast<const u16x8*>(qrow);
  u16x8 qf1 = *reinterpret_cast<const u16x8*>(qrow + 32);

  const u16* kbase = Kb + (size_t)b * Nn * Cn + h * Dn;
  const u16* vbase = Vt + ((size_t)b * Hn + h) * Dn * Nn;

  f32x4 accO[4];
  const f32x4 z = {0.f, 0.f, 0.f, 0.f};
#pragma unroll
  for (int dt = 0; dt < 4; dt++) accO[dt] = z;
  float m = -1e30f, lsum = 0.f;

  for (int kt = 0; kt < Nn; kt += 64){
    // --- QK^T (swapped): st[t][rr] = S[key = kt+16t+4g+rr][query r] ---
    f32x4 st[4];
#pragma unroll
    for (int t = 0; t < 4; t++){
      const u16* kr = kbase + (size_t)(kt + 16*t + r) * Cn;
      u16x8 k0 = *reinterpret_cast<const u16x8*>(kr + 8*g);
      u16x8 k1 = *reinterpret_cast<const u16x8*>(kr + 32 + 8*g);
      st[t] = mfma16(k0, qf0, z);
      st[t] = mfma16(k1, qf1, st[t]);
    }
    // --- per-lane max over 16 scores, sync across the 4 g-copies (2 shuffles) ---
    float tm = fmaxf(fmaxf(st[0][0], st[0][1]), fmaxf(st[0][2], st[0][3]));
#pragma unroll
    for (int t = 1; t < 4; t++)
      tm = fmaxf(tm, fmaxf(fmaxf(st[t][0], st[t][1]), fmaxf(st[t][2], st[t][3])));
    tm = fmaxf(tm, __shfl_xor(tm, 16));
    tm = fmaxf(tm, __shfl_xor(tm, 32));
    // --- defer-max rescale (T13): only when max grew by > 8 ---
    if (__any(tm - m > 8.f)){
      float mn = fmaxf(m, tm);
      float al = __expf(m - mn);
      m = mn;
      lsum *= al;
#pragma unroll
      for (int dt = 0; dt < 4; dt++) accO[dt] *= al;
    }
    // --- exp, pack, LDS exchange ---
    asm volatile("" ::: "memory");
    float ls = 0.f;
#pragma unroll
    for (int t = 0; t < 4; t++){
      float e0 = __expf(st[t][0] - m);
      float e1 = __expf(st[t][1] - m);
      float e2 = __expf(st[t][2] - m);
      float e3 = __expf(st[t][3] - m);
      ls += (e0 + e1) + (e2 + e3);
      u16x4 pk;
      pk[0] = f2bf(e0); pk[1] = f2bf(e1); pk[2] = f2bf(e2); pk[3] = f2bf(e3);
      *reinterpret_cast<u16x4*>(&P[w][r][16*t + 4*g]) = pk;
    }
    lsum += ls;
    asm volatile("s_waitcnt lgkmcnt(0)" ::: "memory");  // wave-internal P exchange
    u16x8 pf0 = *reinterpret_cast<const u16x8*>(&P[w][r][8*g]);
    u16x8 pf1 = *reinterpret_cast<const u16x8*>(&P[w][r][32 + 8*g]);
    // --- PV (swapped): accO[dt] lane holds O[d = dt*16+4g+rr][query r] ---
#pragma unroll
    for (int dt = 0; dt < 4; dt++){
      const u16* vr = vbase + (size_t)(dt*16 + r) * Nn + kt;
      accO[dt] = mfma16(*reinterpret_cast<const u16x8*>(vr + 8*g),      pf0, accO[dt]);
      accO[dt] = mfma16(*reinterpret_cast<const u16x8*>(vr + 32 + 8*g), pf1, accO[dt]);
    }
  }

  // --- epilogue: cross-g lsum reduce, normalize, +L, write token-major bf16 ---
  lsum += __shfl_xor(lsum, 16);
  lsum += __shfl_xor(lsum, 32);
  float linv = 1.0f / lsum;
  const int n = q0 + r;
  const u16* lrow = Lb + ((size_t)b * Nn + n) * Cn + h * Dn;
  u16* trow = tok + ((size_t)b * Nn + n) * Cn + h * Dn;
#pragma unroll
  for (int dt = 0; dt < 4; dt++){
    u16x4 lv = *reinterpret_cast<const u16x4*>(lrow + dt*16 + 4*g);
    u16x4 ov;
#pragma unroll
    for (int rr = 0; rr < 4; rr++)
      ov[rr] = f2bf(accO[dt][rr] * linv + bf2f(lv[rr]));
    *reinterpret_cast<u16x4*>(trow + dt*16 + 4*g) = ov;
  }
}

// ---------------- GEMM2: out = Wout @ tok + bout  -> f32 [B][C][N] ----------------
__global__ __launch_bounds__(256) void k_gemm2(const u16* __restrict__ tok, // [B][N][C]
                                               const u16* __restrict__ Wo,  // [C][C]
                                               const float* __restrict__ bout,
                                               float* __restrict__ out){
  const int ob = blockIdx.x;   // 4 o-blocks of 128
  const int nb = blockIdx.y;   // 8 n-blocks of 128
  const int b  = blockIdx.z;
  const int w = threadIdx.x >> 6, wi = w >> 1, wj = w & 1;
  const int lane = threadIdx.x & 63, r = lane & 15, g = lane >> 4;

  f32x4 acc[4][4];
  const f32x4 z = {0.f, 0.f, 0.f, 0.f};
#pragma unroll
  for (int i = 0; i < 4; i++)
#pragma unroll
    for (int j = 0; j < 4; j++) acc[i][j] = z;

  const u16* Ap = Wo + (size_t)(ob*128 + wi*64) * Cn;
  const u16* Bp = tok + (size_t)b * Nn * Cn + (size_t)(nb*128 + wj*64) * Cn;
  gemm_nt_64x64(Ap, Cn, Bp, Cn, Cn, acc);

#pragma unroll
  for (int it = 0; it < 4; it++)
#pragma unroll
    for (int jt = 0; jt < 4; jt++)
#pragma unroll
      for (int rr = 0; rr < 4; rr++){
        int o = ob*128 + wi*64 + it*16 + 4*g + rr;
        int n = nb*128 + wj*64 + jt*16 + r;
        out[((size_t)b * Cn + o) * Nn + n] = acc[it][jt][rr] + bout[o];
      }
}

extern "C" void kernel_launch(void* const* d_in, const int* in_sizes, int n_in,
                              void* d_out, int out_size, void* d_ws, size_t ws_size,
                              hipStream_t stream){
  const float* fmap  = (const float*)d_in[0];
  const float* Wqkvl = (const float*)d_in[1];
  const float* Wout  = (const float*)d_in[2];
  const float* bout  = (const float*)d_in[3];
  float* out = (float*)d_out;

  char* ws = (char*)d_ws;
  size_t off = 0;
  auto alloc = [&](size_t bytes) -> void* {
    void* p = ws + off;
    off += (bytes + 255) & ~(size_t)255;
    return p;
  };
  u16* W1bf  = (u16*)alloc((size_t)4*Cn*Cn*2);
  u16* Wobf  = (u16*)alloc((size_t)Cn*Cn*2);
  u16* fmapT = (u16*)alloc((size_t)Bn*Nn*Cn*2);
  u16* Qb    = (u16*)alloc((size_t)Bn*Nn*Cn*2);
  u16* Kb    = (u16*)alloc((size_t)Bn*Nn*Cn*2);
  u16* Lb    = (u16*)alloc((size_t)Bn*Nn*Cn*2);
  u16* Vt    = (u16*)alloc((size_t)Bn*Hn*Dn*Nn*2);
  u16* tok   = fmapT;   // fmapT dead after gemm1; reuse for attention output

  hipLaunchKernelGGL(k_convert, dim3((4*Cn*Cn/4 + 255)/256), dim3(256), 0, stream,
                     Wqkvl, W1bf, 4*Cn*Cn/4);
  hipLaunchKernelGGL(k_convert, dim3((Cn*Cn/4 + 255)/256), dim3(256), 0, stream,
                     Wout, Wobf, Cn*Cn/4);
  hipLaunchKernelGGL(k_transpose, dim3(Nn/32, Cn/32, Bn), dim3(256), 0, stream, fmap, fmapT);
  hipLaunchKernelGGL(k_gemm1, dim3(16, 8, Bn), dim3(256), 0, stream, fmapT, W1bf, Qb, Kb, Vt, Lb);
  hipLaunchKernelGGL(k_attn, dim3(1024), dim3(256), 0, stream, Qb, Kb, Vt, Lb, tok);
  hipLaunchKernelGGL(k_gemm2, dim3(4, 8, Bn), dim3(256), 0, stream, tok, Wobf, bout, out);
}